// Round 10
// baseline (550.849 us; speedup 1.0000x reference)
//
#include <hip/hip_runtime.h>
#include <hip/hip_cooperative_groups.h>
#include <math.h>

namespace cg = cooperative_groups;

// Problem constants (from setup_inputs)
#define B_ 4
#define V_ 6
#define C_ 256
#define Q_ 2048
#define KP_ 4
#define H0_ 64
#define W0_ 176
#define H1_ 32
#define W1_ 88
#define RADIUS_ 2.0f

#define HW0_ (H0_ * W0_)   // 11264
#define HW1_ (H1_ * W1_)   // 2816
#define NQ_  (B_ * Q_)     // 8192

#define F0_ELEMS ((size_t)B_ * V_ * C_ * HW0_)   // 69,206,016
#define F1_ELEMS ((size_t)B_ * V_ * C_ * HW1_)   // 17,301,504

#define PXT0_ 176                         // 64-px tiles per (b,v) in L0
#define PXT1_ 44                          // ... in L1
#define PXT_ (PXT0_ + PXT1_)              // 220
#define TILES_PER_B_ (PXT_ * V_ * 4)      // 5280 (64px x 64ch tiles)
#define NT_TILES_ (TILES_PER_B_ * B_)     // 21120

typedef float f4 __attribute__((ext_vector_type(4)));
typedef unsigned short us8 __attribute__((ext_vector_type(8)));

__device__ __forceinline__ unsigned short f2bf(float f) {   // RNE f32->bf16
  const unsigned int x = __float_as_uint(f);
  return (unsigned short)((x + 0x7fffu + ((x >> 16) & 1u)) >> 16);
}
__device__ __forceinline__ float bf2f(unsigned short u) {
  return __uint_as_float((unsigned int)u << 16);
}

// ---------------------------------------------------------------------------
// Projection precompute (unchanged; proven R4-R8)
// ---------------------------------------------------------------------------
__global__ __launch_bounds__(256) void proj_kernel(
    const float* __restrict__ refs, const float* __restrict__ intr,
    const float* __restrict__ extr, float* __restrict__ xy,
    unsigned int* __restrict__ masks, float* __restrict__ invs) {
  const int idx = blockIdx.x * 256 + threadIdx.x;
  if (idx >= NQ_) return;
  const int b = idx >> 11;
  const float rx = refs[(size_t)idx * 3 + 0];
  const float ry = refs[(size_t)idx * 3 + 1];
  const float rz = refs[(size_t)idx * 3 + 2];
  unsigned int mask = 0;
  const size_t base = (size_t)idx * 48;
  for (int v = 0; v < V_; ++v) {
    const float* E = extr + ((size_t)b * V_ + v) * 16;
    const float* K = intr + ((size_t)b * V_ + v) * 9;
    for (int kp = 0; kp < KP_; ++kp) {
      const float kx = (kp == 1) ? RADIUS_ : ((kp == 3) ? -RADIUS_ : 0.f);
      const float ky = (kp == 2) ? RADIUS_ : 0.f;
      const float px = rx + kx, py = ry + ky, pz = rz;
      const float cx = E[0] * px + E[1] * py + E[2]  * pz + E[3];
      const float cy = E[4] * px + E[5] * py + E[6]  * pz + E[7];
      const float cz = E[8] * px + E[9] * py + E[10] * pz + E[11];
      const float uu = K[0] * cx + K[1] * cy + K[2] * cz;
      const float vv = K[3] * cx + K[4] * cy + K[5] * cz;
      const float ww = K[6] * cx + K[7] * cy + K[8] * cz;
      const float zc = fmaxf(ww, 1e-5f);
      const int s = v * KP_ + kp;
      xy[base + 2 * s]     = uu / zc;
      xy[base + 2 * s + 1] = vv / zc;
      if (ww > 0.f) mask |= (1u << s);
    }
  }
  masks[idx] = mask;
  invs[idx] = 0.5f / fmaxf((float)__popc(mask), 1.0f);
}

// ---------------------------------------------------------------------------
// One 64px x 64ch LDS transpose tile (the proven R6 kernel body as a device
// function). All 4 waves of the block cooperate; 2x __syncthreads per tile.
// tt indexes tiles WITHIN batch b: ct = tt&3 (ch tile), then v / px-tile.
// ---------------------------------------------------------------------------
__device__ __forceinline__ void transpose_tile_lds(
    const int b, const int tt, float tile[64][69], const int tid,
    const float* __restrict__ feat0, const float* __restrict__ feat1,
    unsigned short* __restrict__ f0t, unsigned short* __restrict__ f1t) {
  const int ct0 = (tt & 3) * 64;
  const int rest = tt >> 2;            // 0..1319
  const int v = rest / PXT_;
  const int r3 = rest - v * PXT_;
  const int bv = b * V_ + v;

  const float* src; unsigned short* dst; int HW, p0;
  if (r3 < PXT0_) {
    p0 = r3 * 64; src = feat0; dst = f0t; HW = HW0_;
  } else {
    p0 = (r3 - PXT0_) * 64; src = feat1; dst = f1t; HW = HW1_;
  }
  const size_t sbase = (size_t)bv * C_ * HW;
  const size_t dbase = (size_t)bv * HW * C_;

  {  // read-in: coalesced f32x4 along HW
    const int px4 = (tid & 15) * 4;
    const int crow = tid >> 4;
    for (int j = 0; j < 64; j += 16) {
      const f4 v4 = __builtin_nontemporal_load(
          reinterpret_cast<const f4*>(
              src + sbase + (size_t)(ct0 + crow + j) * HW + p0 + px4));
      tile[crow + j][px4 + 0] = v4.x;
      tile[crow + j][px4 + 1] = v4.y;
      tile[crow + j][px4 + 2] = v4.z;
      tile[crow + j][px4 + 3] = v4.w;
    }
  }
  __syncthreads();
  {  // write-out: us8 (16B) coalesced along C
    const int cx8 = (tid & 7) * 8;
    const int prow = tid >> 3;
    for (int j = 0; j < 64; j += 32) {
      us8 o;
      #pragma unroll
      for (int k = 0; k < 8; ++k) o[k] = f2bf(tile[cx8 + k][prow + j]);
      *reinterpret_cast<us8*>(
          dst + dbase + (size_t)(p0 + prow + j) * C_ + ct0 + cx8) = o;
    }
  }
  __syncthreads();
}

// ---------------------------------------------------------------------------
// Sampler body for one query (proven R6/R8 structure)
// ---------------------------------------------------------------------------
__device__ __forceinline__ void sample_query(
    const int idx, const int lane,
    const unsigned short* __restrict__ f0t, const unsigned short* __restrict__ f1t,
    const float* __restrict__ xy, const unsigned int* __restrict__ masks,
    const float* __restrict__ invs, float* __restrict__ out) {
  const int half = lane >> 5;
  const int cidx = lane & 31;
  const int b = idx >> 11;
  const unsigned int mask = masks[idx];
  const float inv = invs[idx];
  const float* pxy = xy + (size_t)idx * 48;
  const int ce = cidx * 8;
  const unsigned short* F0 = f0t + (size_t)b * V_ * HW0_ * C_ + ce;
  const unsigned short* F1 = f1t + (size_t)b * V_ * HW1_ * C_ + ce;

  float acc[8] = {0.f, 0.f, 0.f, 0.f, 0.f, 0.f, 0.f, 0.f};

  #pragma unroll
  for (int s = 0; s < 24; ++s) {
    const bool valid = (mask >> s) & 1u;
    float x = pxy[2 * s], y = pxy[2 * s + 1];
    if (!valid) { x = 0.f; y = 0.f; }
    const float fvalid = valid ? 1.f : 0.f;
    const float x0f = floorf(x), y0f = floorf(y);
    const float wx1 = x - x0f, wy1 = y - y0f;
    const float wx0 = 1.f - wx1, wy0 = 1.f - wy1;
    const int v = s >> 2;

    // level 0: branch-free
    {
      const float Wm1 = (float)(W0_ - 1), Hm1 = (float)(H0_ - 1);
      const float xhf = half ? (x0f + 1.f) : x0f;
      const float bx = (xhf >= 0.f && xhf <= Wm1) ? 1.f : 0.f;
      const float by0 = (y0f >= 0.f && y0f <= Hm1) ? 1.f : 0.f;
      const float by1 = (y0f + 1.f >= 0.f && y0f + 1.f <= Hm1) ? 1.f : 0.f;
      const float wxh = (half ? wx1 : wx0) * bx * fvalid;
      const int xh  = (int)fminf(fmaxf(xhf, 0.f), Wm1);
      const int yi0 = (int)fminf(fmaxf(y0f, 0.f), Hm1);
      const int yi1 = (int)fminf(fmaxf(y0f + 1.f, 0.f), Hm1);
      const float w0 = wxh * wy0 * by0;
      const float w1 = wxh * wy1 * by1;
      const unsigned short* Fv = F0 + (size_t)v * HW0_ * C_;
      const us8 u0 = *reinterpret_cast<const us8*>(Fv + (size_t)(yi0 * W0_ + xh) * C_);
      const us8 u1 = *reinterpret_cast<const us8*>(Fv + (size_t)(yi1 * W0_ + xh) * C_);
      #pragma unroll
      for (int k = 0; k < 8; ++k) {
        acc[k] = fmaf(w0, bf2f(u0[k]), acc[k]);
        acc[k] = fmaf(w1, bf2f(u1[k]), acc[k]);
      }
    }

    // level 1: uniform skip (mostly OOB)
    {
      const float Wm1 = (float)(W1_ - 1), Hm1 = (float)(H1_ - 1);
      const float x1f = x0f + 1.f, y1f = y0f + 1.f;
      const bool bx0 = (x0f >= 0.f) && (x0f <= Wm1);
      const bool bx1 = (x1f >= 0.f) && (x1f <= Wm1);
      const bool by0 = (y0f >= 0.f) && (y0f <= Hm1);
      const bool by1 = (y1f >= 0.f) && (y1f <= Hm1);
      if (((bx0 || bx1) && (by0 || by1)) && valid) {
        const int xi0 = (int)fminf(fmaxf(x0f, 0.f), Wm1);
        const int xi1 = (int)fminf(fmaxf(x1f, 0.f), Wm1);
        const int xh = half ? xi1 : xi0;
        const float wxh = half ? (bx1 ? wx1 : 0.f) : (bx0 ? wx0 : 0.f);
        const unsigned short* Fv = F1 + (size_t)v * HW1_ * C_;
        if (by0) {
          const int yi0 = (int)fminf(fmaxf(y0f, 0.f), Hm1);
          const us8 u = *reinterpret_cast<const us8*>(Fv + (size_t)(yi0 * W1_ + xh) * C_);
          const float w = wxh * wy0;
          #pragma unroll
          for (int k = 0; k < 8; ++k) acc[k] = fmaf(w, bf2f(u[k]), acc[k]);
        }
        if (by1) {
          const int yi1 = (int)fminf(fmaxf(y1f, 0.f), Hm1);
          const us8 u = *reinterpret_cast<const us8*>(Fv + (size_t)(yi1 * W1_ + xh) * C_);
          const float w = wxh * wy1;
          #pragma unroll
          for (int k = 0; k < 8; ++k) acc[k] = fmaf(w, bf2f(u[k]), acc[k]);
        }
      }
    }
  }

  #pragma unroll
  for (int k = 0; k < 8; ++k) acc[k] += __shfl_xor(acc[k], 32);

  f4 o;
  const int ko = half * 4;
  o.x = acc[ko + 0] * inv;
  o.y = acc[ko + 1] * inv;
  o.z = acc[ko + 2] * inv;
  o.w = acc[ko + 3] * inv;
  __builtin_nontemporal_store(
      o, reinterpret_cast<f4*>(out + (size_t)idx * C_ + ce + ko));
}

// ---------------------------------------------------------------------------
// Cooperative pipeline: 5 phases; grid.sync between (proven-correct in R8).
// Per phase: block-strided LDS transpose of batch ph overlapped (by block
// parity ordering) with wave-strided sampling of batch ph-1.
// ---------------------------------------------------------------------------
__global__ __launch_bounds__(256) void fused_coop(
    const float* __restrict__ feat0, const float* __restrict__ feat1,
    unsigned short* __restrict__ f0t, unsigned short* __restrict__ f1t,
    const float* __restrict__ xy, const unsigned int* __restrict__ masks,
    const float* __restrict__ invs, float* __restrict__ out,
    const int nblocks) {
  cg::grid_group grid = cg::this_grid();
  __shared__ float tile[64][69];
  const int blk = (int)blockIdx.x;
  const int tid = (int)threadIdx.x;
  const int gw = blk * 4 + (tid >> 6);
  const int nw = nblocks * 4;
  const int lane = tid & 63;
  const bool sfirst = (blk & 1);

  for (int ph = 0; ph <= B_; ++ph) {
    const int sb = ph - 1;
    if (sfirst && sb >= 0)
      for (int q = gw; q < Q_; q += nw)
        sample_query(sb * Q_ + q, lane, f0t, f1t, xy, masks, invs, out);
    if (ph < B_)
      for (int tt = blk; tt < TILES_PER_B_; tt += nblocks)
        transpose_tile_lds(ph, tt, tile, tid, feat0, feat1, f0t, f1t);
    if (!sfirst && sb >= 0)
      for (int q = gw; q < Q_; q += nw)
        sample_query(sb * Q_ + q, lane, f0t, f1t, xy, masks, invs, out);
    grid.sync();
  }
}

// ---------------------------------------------------------------------------
// Serial fallback (R6 flow, known-good ~155us) if cooperative unavailable.
// ---------------------------------------------------------------------------
__global__ __launch_bounds__(256) void transpose_all(
    const float* __restrict__ feat0, const float* __restrict__ feat1,
    unsigned short* __restrict__ f0t, unsigned short* __restrict__ f1t) {
  __shared__ float tile[64][69];
  const int t = (int)blockIdx.x;
  const int b = t / TILES_PER_B_;
  transpose_tile_lds(b, t - b * TILES_PER_B_, tile, (int)threadIdx.x,
                     feat0, feat1, f0t, f1t);
}

__global__ __launch_bounds__(256) void sampler_only(
    const unsigned short* __restrict__ f0t, const unsigned short* __restrict__ f1t,
    const float* __restrict__ xy, const unsigned int* __restrict__ masks,
    const float* __restrict__ invs, float* __restrict__ out) {
  const int idx = (int)(blockIdx.x * 4 + (threadIdx.x >> 6));
  sample_query(idx, threadIdx.x & 63, f0t, f1t, xy, masks, invs, out);
}

// ---------------------------------------------------------------------------
// Last-resort fallback: direct gather from [B,V,C,H,W] (tiny workspace)
// ---------------------------------------------------------------------------
__device__ __forceinline__ float bilinear_scalar(
    const float* __restrict__ fm, const int W, const int H,
    const float x, const float y) {
  const float x0f = floorf(x), y0f = floorf(y);
  const float wx1 = x - x0f, wy1 = y - y0f;
  const float wx0 = 1.f - wx1, wy0 = 1.f - wy1;
  const float x1f = x0f + 1.f, y1f = y0f + 1.f;
  const float Wm1 = (float)(W - 1), Hm1 = (float)(H - 1);
  const bool bx0 = (x0f >= 0.f) && (x0f <= Wm1);
  const bool bx1 = (x1f >= 0.f) && (x1f <= Wm1);
  const bool by0 = (y0f >= 0.f) && (y0f <= Hm1);
  const bool by1 = (y1f >= 0.f) && (y1f <= Hm1);
  if (!((bx0 || bx1) && (by0 || by1))) return 0.f;
  const int xi0 = (int)fminf(fmaxf(x0f, 0.f), Wm1);
  const int xi1 = (int)fminf(fmaxf(x1f, 0.f), Wm1);
  const int yi0 = (int)fminf(fmaxf(y0f, 0.f), Hm1);
  const int yi1 = (int)fminf(fmaxf(y1f, 0.f), Hm1);
  float r = 0.f;
  if (bx0 && by0) r = fmaf(wx0 * wy0, fm[yi0 * W + xi0], r);
  if (bx1 && by0) r = fmaf(wx1 * wy0, fm[yi0 * W + xi1], r);
  if (bx0 && by1) r = fmaf(wx0 * wy1, fm[yi1 * W + xi0], r);
  if (bx1 && by1) r = fmaf(wx1 * wy1, fm[yi1 * W + xi1], r);
  return r;
}

__global__ __launch_bounds__(256) void sampler_direct(
    const float* __restrict__ f0, const float* __restrict__ f1,
    const float* __restrict__ refs, const float* __restrict__ intr,
    const float* __restrict__ extr, float* __restrict__ out) {
  __shared__ float sx[24], sy[24], scnt;
  __shared__ unsigned int smask;
  const int tid = threadIdx.x;
  const int b = blockIdx.y, q = blockIdx.x;
  bool zvalid = false;
  if (tid < 24) {
    const int v = tid >> 2, kp = tid & 3;
    const float kx = (kp == 1) ? RADIUS_ : ((kp == 3) ? -RADIUS_ : 0.f);
    const float ky = (kp == 2) ? RADIUS_ : 0.f;
    const float rx = refs[((size_t)b * Q_ + q) * 3 + 0];
    const float ry = refs[((size_t)b * Q_ + q) * 3 + 1];
    const float rz = refs[((size_t)b * Q_ + q) * 3 + 2];
    const float px = rx + kx, py = ry + ky, pz = rz;
    const float* E = extr + ((size_t)b * V_ + v) * 16;
    const float cx = E[0] * px + E[1] * py + E[2]  * pz + E[3];
    const float cy = E[4] * px + E[5] * py + E[6]  * pz + E[7];
    const float cz = E[8] * px + E[9] * py + E[10] * pz + E[11];
    const float* K = intr + ((size_t)b * V_ + v) * 9;
    const float uu = K[0] * cx + K[1] * cy + K[2] * cz;
    const float vv = K[3] * cx + K[4] * cy + K[5] * cz;
    const float ww = K[6] * cx + K[7] * cy + K[8] * cz;
    const float zc = fmaxf(ww, 1e-5f);
    sx[tid] = uu / zc;
    sy[tid] = vv / zc;
    zvalid = (ww > 0.f);
  }
  const unsigned long long m = __ballot(zvalid);
  if (tid == 0) {
    const unsigned int mm = (unsigned int)(m & 0xFFFFFFULL);
    smask = mm;
    scnt = fmaxf((float)__popc(mm), 1.0f);
  }
  __syncthreads();
  const unsigned int mask = smask;
  const float cnt = scnt;
  const int c = tid;
  float a0 = 0.f, a1 = 0.f;
  for (int s = 0; s < 24; ++s) {
    if (!((mask >> s) & 1u)) continue;
    const float x = sx[s], y = sy[s];
    const int v = s >> 2;
    const size_t bv = (size_t)b * V_ + v;
    a0 += bilinear_scalar(f0 + (bv * C_ + c) * (size_t)HW0_, W0_, H0_, x, y);
    a1 += bilinear_scalar(f1 + (bv * C_ + c) * (size_t)HW1_, W1_, H1_, x, y);
  }
  out[((size_t)b * Q_ + q) * C_ + c] = (a0 + a1) * 0.5f / cnt;
}

// ---------------------------------------------------------------------------
extern "C" void kernel_launch(void* const* d_in, const int* in_sizes, int n_in,
                              void* d_out, int out_size, void* d_ws, size_t ws_size,
                              hipStream_t stream) {
  const float* feat0 = (const float*)d_in[0];
  const float* feat1 = (const float*)d_in[1];
  const float* refs  = (const float*)d_in[2];
  const float* intr  = (const float*)d_in[3];
  const float* extr  = (const float*)d_in[4];
  float* out = (float*)d_out;

  const size_t need = F0_ELEMS * 2 + F1_ELEMS * 2
                    + ((size_t)NQ_ * 48 + 2 * NQ_) * 4;

  if (ws_size < need) {
    sampler_direct<<<dim3(Q_, B_), 256, 0, stream>>>(
        feat0, feat1, refs, intr, extr, out);
    return;
  }

  unsigned short* f0t = (unsigned short*)d_ws;
  unsigned short* f1t = f0t + F0_ELEMS;
  float* xy = (float*)(f1t + F1_ELEMS);
  unsigned int* masks = (unsigned int*)(xy + (size_t)NQ_ * 48);
  float* invs = (float*)(masks + NQ_);

  proj_kernel<<<NQ_ / 256, 256, 0, stream>>>(refs, intr, extr, xy, masks, invs);

  // Cooperative pipelined path
  int maxActive = 0;
  hipError_t qerr = hipOccupancyMaxActiveBlocksPerMultiprocessor(
      &maxActive, fused_coop, 256, 0);
  bool coop_ok = false;
  if (qerr == hipSuccess && maxActive > 0) {
    int nblocks = maxActive * 256;          // 256 CUs on MI355X
    if (nblocks > 512) nblocks = 512;       // 512 -> exactly 1 query/wave/phase
    void* args[] = {(void*)&feat0, (void*)&feat1, (void*)&f0t, (void*)&f1t,
                    (void*)&xy, (void*)&masks, (void*)&invs, (void*)&out,
                    (void*)&nblocks};
    hipError_t lerr = hipLaunchCooperativeKernel(
        (const void*)fused_coop, dim3(nblocks), dim3(256), args, 0, stream);
    coop_ok = (lerr == hipSuccess);
  }

  if (!coop_ok) {
    // Serial fallback (R6 flow)
    transpose_all<<<NT_TILES_, 256, 0, stream>>>(feat0, feat1, f0t, f1t);
    sampler_only<<<NQ_ / 4, 256, 0, stream>>>(f0t, f1t, xy, masks, invs, out);
  }
}

// Round 11
// 155.214 us; speedup vs baseline: 3.5490x; 3.5490x over previous
//
#include <hip/hip_runtime.h>
#include <hip/hip_cooperative_groups.h>
#include <math.h>

namespace cg = cooperative_groups;

// Problem constants (from setup_inputs)
#define B_ 4
#define V_ 6
#define C_ 256
#define Q_ 2048
#define KP_ 4
#define H0_ 64
#define W0_ 176
#define H1_ 32
#define W1_ 88
#define RADIUS_ 2.0f

#define HW0_ (H0_ * W0_)   // 11264
#define HW1_ (H1_ * W1_)   // 2816
#define NQ_  (B_ * Q_)     // 8192

#define F0_ELEMS ((size_t)B_ * V_ * C_ * HW0_)   // 69,206,016
#define F1_ELEMS ((size_t)B_ * V_ * C_ * HW1_)   // 17,301,504

#define PXT0_ 176                         // 64-px tiles per (b,v) in L0
#define PXT1_ 44                          // ... in L1
#define PXT_ (PXT0_ + PXT1_)              // 220
#define TILES_PER_B_ (PXT_ * V_ * 4)      // 5280 (64px x 64ch tiles)
#define NT_TILES_ (TILES_PER_B_ * B_)     // 21120

typedef float f4 __attribute__((ext_vector_type(4)));
typedef unsigned short us8 __attribute__((ext_vector_type(8)));

__device__ __forceinline__ unsigned short f2bf(float f) {   // RNE f32->bf16
  const unsigned int x = __float_as_uint(f);
  return (unsigned short)((x + 0x7fffu + ((x >> 16) & 1u)) >> 16);
}
__device__ __forceinline__ float bf2f(unsigned short u) {
  return __uint_as_float((unsigned int)u << 16);
}

// ---------------------------------------------------------------------------
// Projection precompute (proven R4-R10)
// ---------------------------------------------------------------------------
__global__ __launch_bounds__(256) void proj_kernel(
    const float* __restrict__ refs, const float* __restrict__ intr,
    const float* __restrict__ extr, float* __restrict__ xy,
    unsigned int* __restrict__ masks, float* __restrict__ invs) {
  const int idx = blockIdx.x * 256 + threadIdx.x;
  if (idx >= NQ_) return;
  const int b = idx >> 11;
  const float rx = refs[(size_t)idx * 3 + 0];
  const float ry = refs[(size_t)idx * 3 + 1];
  const float rz = refs[(size_t)idx * 3 + 2];
  unsigned int mask = 0;
  const size_t base = (size_t)idx * 48;
  for (int v = 0; v < V_; ++v) {
    const float* E = extr + ((size_t)b * V_ + v) * 16;
    const float* K = intr + ((size_t)b * V_ + v) * 9;
    for (int kp = 0; kp < KP_; ++kp) {
      const float kx = (kp == 1) ? RADIUS_ : ((kp == 3) ? -RADIUS_ : 0.f);
      const float ky = (kp == 2) ? RADIUS_ : 0.f;
      const float px = rx + kx, py = ry + ky, pz = rz;
      const float cx = E[0] * px + E[1] * py + E[2]  * pz + E[3];
      const float cy = E[4] * px + E[5] * py + E[6]  * pz + E[7];
      const float cz = E[8] * px + E[9] * py + E[10] * pz + E[11];
      const float uu = K[0] * cx + K[1] * cy + K[2] * cz;
      const float vv = K[3] * cx + K[4] * cy + K[5] * cz;
      const float ww = K[6] * cx + K[7] * cy + K[8] * cz;
      const float zc = fmaxf(ww, 1e-5f);
      const int s = v * KP_ + kp;
      xy[base + 2 * s]     = uu / zc;
      xy[base + 2 * s + 1] = vv / zc;
      if (ww > 0.f) mask |= (1u << s);
    }
  }
  masks[idx] = mask;
  invs[idx] = 0.5f / fmaxf((float)__popc(mask), 1.0f);
}

// ---------------------------------------------------------------------------
// One 64px x 64ch LDS transpose tile (proven body). 4 waves cooperate.
// ---------------------------------------------------------------------------
__device__ __forceinline__ void transpose_tile_lds(
    const int b, const int tt, float tile[64][69], const int tid,
    const float* __restrict__ feat0, const float* __restrict__ feat1,
    unsigned short* __restrict__ f0t, unsigned short* __restrict__ f1t) {
  const int ct0 = (tt & 3) * 64;
  const int rest = tt >> 2;            // 0..1319
  const int v = rest / PXT_;
  const int r3 = rest - v * PXT_;
  const int bv = b * V_ + v;

  const float* src; unsigned short* dst; int HW, p0;
  if (r3 < PXT0_) {
    p0 = r3 * 64; src = feat0; dst = f0t; HW = HW0_;
  } else {
    p0 = (r3 - PXT0_) * 64; src = feat1; dst = f1t; HW = HW1_;
  }
  const size_t sbase = (size_t)bv * C_ * HW;
  const size_t dbase = (size_t)bv * HW * C_;

  {  // read-in: coalesced f32x4 along HW
    const int px4 = (tid & 15) * 4;
    const int crow = tid >> 4;
    for (int j = 0; j < 64; j += 16) {
      const f4 v4 = __builtin_nontemporal_load(
          reinterpret_cast<const f4*>(
              src + sbase + (size_t)(ct0 + crow + j) * HW + p0 + px4));
      tile[crow + j][px4 + 0] = v4.x;
      tile[crow + j][px4 + 1] = v4.y;
      tile[crow + j][px4 + 2] = v4.z;
      tile[crow + j][px4 + 3] = v4.w;
    }
  }
  __syncthreads();
  {  // write-out: us8 (16B) coalesced along C
    const int cx8 = (tid & 7) * 8;
    const int prow = tid >> 3;
    for (int j = 0; j < 64; j += 32) {
      us8 o;
      #pragma unroll
      for (int k = 0; k < 8; ++k) o[k] = f2bf(tile[cx8 + k][prow + j]);
      *reinterpret_cast<us8*>(
          dst + dbase + (size_t)(p0 + prow + j) * C_ + ct0 + cx8) = o;
    }
  }
  __syncthreads();
}

// ---------------------------------------------------------------------------
// Sampler body for one query (proven R6/R8/R10 structure)
// ---------------------------------------------------------------------------
__device__ __forceinline__ void sample_query(
    const int idx, const int lane,
    const unsigned short* __restrict__ f0t, const unsigned short* __restrict__ f1t,
    const float* __restrict__ xy, const unsigned int* __restrict__ masks,
    const float* __restrict__ invs, float* __restrict__ out) {
  const int half = lane >> 5;
  const int cidx = lane & 31;
  const int b = idx >> 11;
  const unsigned int mask = masks[idx];
  const float inv = invs[idx];
  const float* pxy = xy + (size_t)idx * 48;
  const int ce = cidx * 8;
  const unsigned short* F0 = f0t + (size_t)b * V_ * HW0_ * C_ + ce;
  const unsigned short* F1 = f1t + (size_t)b * V_ * HW1_ * C_ + ce;

  float acc[8] = {0.f, 0.f, 0.f, 0.f, 0.f, 0.f, 0.f, 0.f};

  #pragma unroll
  for (int s = 0; s < 24; ++s) {
    const bool valid = (mask >> s) & 1u;
    float x = pxy[2 * s], y = pxy[2 * s + 1];
    if (!valid) { x = 0.f; y = 0.f; }
    const float fvalid = valid ? 1.f : 0.f;
    const float x0f = floorf(x), y0f = floorf(y);
    const float wx1 = x - x0f, wy1 = y - y0f;
    const float wx0 = 1.f - wx1, wy0 = 1.f - wy1;
    const int v = s >> 2;

    // level 0: branch-free
    {
      const float Wm1 = (float)(W0_ - 1), Hm1 = (float)(H0_ - 1);
      const float xhf = half ? (x0f + 1.f) : x0f;
      const float bx = (xhf >= 0.f && xhf <= Wm1) ? 1.f : 0.f;
      const float by0 = (y0f >= 0.f && y0f <= Hm1) ? 1.f : 0.f;
      const float by1 = (y0f + 1.f >= 0.f && y0f + 1.f <= Hm1) ? 1.f : 0.f;
      const float wxh = (half ? wx1 : wx0) * bx * fvalid;
      const int xh  = (int)fminf(fmaxf(xhf, 0.f), Wm1);
      const int yi0 = (int)fminf(fmaxf(y0f, 0.f), Hm1);
      const int yi1 = (int)fminf(fmaxf(y0f + 1.f, 0.f), Hm1);
      const float w0 = wxh * wy0 * by0;
      const float w1 = wxh * wy1 * by1;
      const unsigned short* Fv = F0 + (size_t)v * HW0_ * C_;
      const us8 u0 = *reinterpret_cast<const us8*>(Fv + (size_t)(yi0 * W0_ + xh) * C_);
      const us8 u1 = *reinterpret_cast<const us8*>(Fv + (size_t)(yi1 * W0_ + xh) * C_);
      #pragma unroll
      for (int k = 0; k < 8; ++k) {
        acc[k] = fmaf(w0, bf2f(u0[k]), acc[k]);
        acc[k] = fmaf(w1, bf2f(u1[k]), acc[k]);
      }
    }

    // level 1: uniform skip (mostly OOB)
    {
      const float Wm1 = (float)(W1_ - 1), Hm1 = (float)(H1_ - 1);
      const float x1f = x0f + 1.f, y1f = y0f + 1.f;
      const bool bx0 = (x0f >= 0.f) && (x0f <= Wm1);
      const bool bx1 = (x1f >= 0.f) && (x1f <= Wm1);
      const bool by0 = (y0f >= 0.f) && (y0f <= Hm1);
      const bool by1 = (y1f >= 0.f) && (y1f <= Hm1);
      if (((bx0 || bx1) && (by0 || by1)) && valid) {
        const int xi0 = (int)fminf(fmaxf(x0f, 0.f), Wm1);
        const int xi1 = (int)fminf(fmaxf(x1f, 0.f), Wm1);
        const int xh = half ? xi1 : xi0;
        const float wxh = half ? (bx1 ? wx1 : 0.f) : (bx0 ? wx0 : 0.f);
        const unsigned short* Fv = F1 + (size_t)v * HW1_ * C_;
        if (by0) {
          const int yi0 = (int)fminf(fmaxf(y0f, 0.f), Hm1);
          const us8 u = *reinterpret_cast<const us8*>(Fv + (size_t)(yi0 * W1_ + xh) * C_);
          const float w = wxh * wy0;
          #pragma unroll
          for (int k = 0; k < 8; ++k) acc[k] = fmaf(w, bf2f(u[k]), acc[k]);
        }
        if (by1) {
          const int yi1 = (int)fminf(fmaxf(y1f, 0.f), Hm1);
          const us8 u = *reinterpret_cast<const us8*>(Fv + (size_t)(yi1 * W1_ + xh) * C_);
          const float w = wxh * wy1;
          #pragma unroll
          for (int k = 0; k < 8; ++k) acc[k] = fmaf(w, bf2f(u[k]), acc[k]);
        }
      }
    }
  }

  #pragma unroll
  for (int k = 0; k < 8; ++k) acc[k] += __shfl_xor(acc[k], 32);

  f4 o;
  const int ko = half * 4;
  o.x = acc[ko + 0] * inv;
  o.y = acc[ko + 1] * inv;
  o.z = acc[ko + 2] * inv;
  o.w = acc[ko + 3] * inv;
  __builtin_nontemporal_store(
      o, reinterpret_cast<f4*>(out + (size_t)idx * C_ + ce + ko));
}

// ---------------------------------------------------------------------------
// Cooperative pipeline at FULL occupancy. Queries remapped to the top-quarter
// waves (which live in the 2-tile blocks) so per-block T+S work is balanced.
// ---------------------------------------------------------------------------
__global__ __launch_bounds__(256) void fused_coop(
    const float* __restrict__ feat0, const float* __restrict__ feat1,
    unsigned short* __restrict__ f0t, unsigned short* __restrict__ f1t,
    const float* __restrict__ xy, const unsigned int* __restrict__ masks,
    const float* __restrict__ invs, float* __restrict__ out,
    const int nblocks) {
  cg::grid_group grid = cg::this_grid();
  __shared__ float tile[64][69];
  const int blk = (int)blockIdx.x;
  const int tid = (int)threadIdx.x;
  const int nw = nblocks * 4;
  const int gw = blk * 4 + (tid >> 6);
  const int sgw = (gw + Q_) % nw;      // remap: S waves land in high blocks
  const int lane = tid & 63;
  const bool sfirst = (blk >= nblocks - nblocks / 4);

  for (int ph = 0; ph <= B_; ++ph) {
    const int sb = ph - 1;
    if (sfirst && sb >= 0)
      for (int q = sgw; q < Q_; q += nw)
        sample_query(sb * Q_ + q, lane, f0t, f1t, xy, masks, invs, out);
    if (ph < B_)
      for (int tt = blk; tt < TILES_PER_B_; tt += nblocks)
        transpose_tile_lds(ph, tt, tile, tid, feat0, feat1, f0t, f1t);
    if (!sfirst && sb >= 0)
      for (int q = sgw; q < Q_; q += nw)
        sample_query(sb * Q_ + q, lane, f0t, f1t, xy, masks, invs, out);
    grid.sync();
  }
}

// ---------------------------------------------------------------------------
// Serial fallback (R6 flow, known-good ~155us)
// ---------------------------------------------------------------------------
__global__ __launch_bounds__(256) void transpose_all(
    const float* __restrict__ feat0, const float* __restrict__ feat1,
    unsigned short* __restrict__ f0t, unsigned short* __restrict__ f1t) {
  __shared__ float tile[64][69];
  const int t = (int)blockIdx.x;
  const int b = t / TILES_PER_B_;
  transpose_tile_lds(b, t - b * TILES_PER_B_, tile, (int)threadIdx.x,
                     feat0, feat1, f0t, f1t);
}

__global__ __launch_bounds__(256) void sampler_only(
    const unsigned short* __restrict__ f0t, const unsigned short* __restrict__ f1t,
    const float* __restrict__ xy, const unsigned int* __restrict__ masks,
    const float* __restrict__ invs, float* __restrict__ out) {
  const int idx = (int)(blockIdx.x * 4 + (threadIdx.x >> 6));
  sample_query(idx, threadIdx.x & 63, f0t, f1t, xy, masks, invs, out);
}

// ---------------------------------------------------------------------------
// Last-resort fallback: direct gather from [B,V,C,H,W] (tiny workspace)
// ---------------------------------------------------------------------------
__device__ __forceinline__ float bilinear_scalar(
    const float* __restrict__ fm, const int W, const int H,
    const float x, const float y) {
  const float x0f = floorf(x), y0f = floorf(y);
  const float wx1 = x - x0f, wy1 = y - y0f;
  const float wx0 = 1.f - wx1, wy0 = 1.f - wy1;
  const float x1f = x0f + 1.f, y1f = y0f + 1.f;
  const float Wm1 = (float)(W - 1), Hm1 = (float)(H - 1);
  const bool bx0 = (x0f >= 0.f) && (x0f <= Wm1);
  const bool bx1 = (x1f >= 0.f) && (x1f <= Wm1);
  const bool by0 = (y0f >= 0.f) && (y0f <= Hm1);
  const bool by1 = (y1f >= 0.f) && (y1f <= Hm1);
  if (!((bx0 || bx1) && (by0 || by1))) return 0.f;
  const int xi0 = (int)fminf(fmaxf(x0f, 0.f), Wm1);
  const int xi1 = (int)fminf(fmaxf(x1f, 0.f), Wm1);
  const int yi0 = (int)fminf(fmaxf(y0f, 0.f), Hm1);
  const int yi1 = (int)fminf(fmaxf(y1f, 0.f), Hm1);
  float r = 0.f;
  if (bx0 && by0) r = fmaf(wx0 * wy0, fm[yi0 * W + xi0], r);
  if (bx1 && by0) r = fmaf(wx1 * wy0, fm[yi0 * W + xi1], r);
  if (bx0 && by1) r = fmaf(wx0 * wy1, fm[yi1 * W + xi0], r);
  if (bx1 && by1) r = fmaf(wx1 * wy1, fm[yi1 * W + xi1], r);
  return r;
}

__global__ __launch_bounds__(256) void sampler_direct(
    const float* __restrict__ f0, const float* __restrict__ f1,
    const float* __restrict__ refs, const float* __restrict__ intr,
    const float* __restrict__ extr, float* __restrict__ out) {
  __shared__ float sx[24], sy[24], scnt;
  __shared__ unsigned int smask;
  const int tid = threadIdx.x;
  const int b = blockIdx.y, q = blockIdx.x;
  bool zvalid = false;
  if (tid < 24) {
    const int v = tid >> 2, kp = tid & 3;
    const float kx = (kp == 1) ? RADIUS_ : ((kp == 3) ? -RADIUS_ : 0.f);
    const float ky = (kp == 2) ? RADIUS_ : 0.f;
    const float rx = refs[((size_t)b * Q_ + q) * 3 + 0];
    const float ry = refs[((size_t)b * Q_ + q) * 3 + 1];
    const float rz = refs[((size_t)b * Q_ + q) * 3 + 2];
    const float px = rx + kx, py = ry + ky, pz = rz;
    const float* E = extr + ((size_t)b * V_ + v) * 16;
    const float cx = E[0] * px + E[1] * py + E[2]  * pz + E[3];
    const float cy = E[4] * px + E[5] * py + E[6]  * pz + E[7];
    const float cz = E[8] * px + E[9] * py + E[10] * pz + E[11];
    const float* K = intr + ((size_t)b * V_ + v) * 9;
    const float uu = K[0] * cx + K[1] * cy + K[2] * cz;
    const float vv = K[3] * cx + K[4] * cy + K[5] * cz;
    const float ww = K[6] * cx + K[7] * cy + K[8] * cz;
    const float zc = fmaxf(ww, 1e-5f);
    sx[tid] = uu / zc;
    sy[tid] = vv / zc;
    zvalid = (ww > 0.f);
  }
  const unsigned long long m = __ballot(zvalid);
  if (tid == 0) {
    const unsigned int mm = (unsigned int)(m & 0xFFFFFFULL);
    smask = mm;
    scnt = fmaxf((float)__popc(mm), 1.0f);
  }
  __syncthreads();
  const unsigned int mask = smask;
  const float cnt = scnt;
  const int c = tid;
  float a0 = 0.f, a1 = 0.f;
  for (int s = 0; s < 24; ++s) {
    if (!((mask >> s) & 1u)) continue;
    const float x = sx[s], y = sy[s];
    const int v = s >> 2;
    const size_t bv = (size_t)b * V_ + v;
    a0 += bilinear_scalar(f0 + (bv * C_ + c) * (size_t)HW0_, W0_, H0_, x, y);
    a1 += bilinear_scalar(f1 + (bv * C_ + c) * (size_t)HW1_, W1_, H1_, x, y);
  }
  out[((size_t)b * Q_ + q) * C_ + c] = (a0 + a1) * 0.5f / cnt;
}

// ---------------------------------------------------------------------------
extern "C" void kernel_launch(void* const* d_in, const int* in_sizes, int n_in,
                              void* d_out, int out_size, void* d_ws, size_t ws_size,
                              hipStream_t stream) {
  const float* feat0 = (const float*)d_in[0];
  const float* feat1 = (const float*)d_in[1];
  const float* refs  = (const float*)d_in[2];
  const float* intr  = (const float*)d_in[3];
  const float* extr  = (const float*)d_in[4];
  float* out = (float*)d_out;

  const size_t need = F0_ELEMS * 2 + F1_ELEMS * 2
                    + ((size_t)NQ_ * 48 + 2 * NQ_) * 4;

  if (ws_size < need) {
    sampler_direct<<<dim3(Q_, B_), 256, 0, stream>>>(
        feat0, feat1, refs, intr, extr, out);
    return;
  }

  unsigned short* f0t = (unsigned short*)d_ws;
  unsigned short* f1t = f0t + F0_ELEMS;
  float* xy = (float*)(f1t + F1_ELEMS);
  unsigned int* masks = (unsigned int*)(xy + (size_t)NQ_ * 48);
  float* invs = (float*)(masks + NQ_);

  proj_kernel<<<NQ_ / 256, 256, 0, stream>>>(refs, intr, extr, xy, masks, invs);

  // Cooperative pipelined path at FULL occupancy
  int maxActive = 0;
  hipError_t qerr = hipOccupancyMaxActiveBlocksPerMultiprocessor(
      &maxActive, fused_coop, 256, 0);
  bool coop_ok = false;
  if (qerr == hipSuccess && maxActive >= 6) {   // need high occupancy to win
    int nblocks = maxActive * 256;              // 256 CUs on MI355X
    if (nblocks > 2048) nblocks = 2048;
    void* args[] = {(void*)&feat0, (void*)&feat1, (void*)&f0t, (void*)&f1t,
                    (void*)&xy, (void*)&masks, (void*)&invs, (void*)&out,
                    (void*)&nblocks};
    hipError_t lerr = hipLaunchCooperativeKernel(
        (const void*)fused_coop, dim3(nblocks), dim3(256), args, 0, stream);
    coop_ok = (lerr == hipSuccess);
  }

  if (!coop_ok) {
    // Serial fallback (R6 flow)
    transpose_all<<<NT_TILES_, 256, 0, stream>>>(feat0, feat1, f0t, f1t);
    sampler_only<<<NQ_ / 4, 256, 0, stream>>>(f0t, f1t, xy, masks, invs, out);
  }
}

// Round 12
// 151.267 us; speedup vs baseline: 3.6416x; 1.0261x over previous
//
#include <hip/hip_runtime.h>
#include <math.h>

// Problem constants (from setup_inputs)
#define B_ 4
#define V_ 6
#define C_ 256
#define Q_ 2048
#define KP_ 4
#define H0_ 64
#define W0_ 176
#define H1_ 32
#define W1_ 88
#define RADIUS_ 2.0f

#define HW0_ (H0_ * W0_)   // 11264
#define HW1_ (H1_ * W1_)   // 2816
#define NQ_  (B_ * Q_)     // 8192

#define F0_ELEMS ((size_t)B_ * V_ * C_ * HW0_)   // 69,206,016
#define F1_ELEMS ((size_t)B_ * V_ * C_ * HW1_)   // 17,301,504

// tiles of 64 pixels x 64 channels
#define T0_TILES_ (HW0_ / 64 * B_ * V_)   // 176*24 = 4224
#define T1_TILES_ (HW1_ / 64 * B_ * V_)   // 44*24  = 1056

typedef float f4 __attribute__((ext_vector_type(4)));
typedef unsigned short us8 __attribute__((ext_vector_type(8)));

__device__ __forceinline__ unsigned short f2bf(float f) {   // RNE f32->bf16
  const unsigned int x = __float_as_uint(f);
  return (unsigned short)((x + 0x7fffu + ((x >> 16) & 1u)) >> 16);
}
__device__ __forceinline__ float bf2f(unsigned short u) {
  return __uint_as_float((unsigned int)u << 16);
}

// ---------------------------------------------------------------------------
// Projection precompute (proven R4-R11)
// ---------------------------------------------------------------------------
__global__ __launch_bounds__(256) void proj_kernel(
    const float* __restrict__ refs,   // [B,Q,3]
    const float* __restrict__ intr,   // [B,V,3,3]
    const float* __restrict__ extr,   // [B,V,4,4]
    float* __restrict__ xy,           // [NQ,24,2]
    unsigned int* __restrict__ masks, float* __restrict__ invs) {
  const int idx = blockIdx.x * 256 + threadIdx.x;   // b*Q + q
  if (idx >= NQ_) return;
  const int b = idx >> 11;
  const float rx = refs[(size_t)idx * 3 + 0];
  const float ry = refs[(size_t)idx * 3 + 1];
  const float rz = refs[(size_t)idx * 3 + 2];
  unsigned int mask = 0;
  const size_t base = (size_t)idx * 48;
  for (int v = 0; v < V_; ++v) {
    const float* E = extr + ((size_t)b * V_ + v) * 16;
    const float* K = intr + ((size_t)b * V_ + v) * 9;
    for (int kp = 0; kp < KP_; ++kp) {
      const float kx = (kp == 1) ? RADIUS_ : ((kp == 3) ? -RADIUS_ : 0.f);
      const float ky = (kp == 2) ? RADIUS_ : 0.f;
      const float px = rx + kx, py = ry + ky, pz = rz;
      const float cx = E[0] * px + E[1] * py + E[2]  * pz + E[3];
      const float cy = E[4] * px + E[5] * py + E[6]  * pz + E[7];
      const float cz = E[8] * px + E[9] * py + E[10] * pz + E[11];
      const float uu = K[0] * cx + K[1] * cy + K[2] * cz;
      const float vv = K[3] * cx + K[4] * cy + K[5] * cz;
      const float ww = K[6] * cx + K[7] * cy + K[8] * cz;
      const float zc = fmaxf(ww, 1e-5f);
      const int s = v * KP_ + kp;
      xy[base + 2 * s]     = uu / zc;
      xy[base + 2 * s + 1] = vv / zc;
      if (ww > 0.f) mask |= (1u << s);
    }
  }
  masks[idx] = mask;
  invs[idx] = 0.5f / fmaxf((float)__popc(mask), 1.0f);
}

// ---------------------------------------------------------------------------
// Transpose CHW f32 -> HWC bf16, both levels in one launch (R6, measured
// ~86us at ~6 TB/s). LDS stride 69 keeps both phases at free 2-way conflicts.
// ---------------------------------------------------------------------------
__global__ __launch_bounds__(256) void transpose_bf16(
    const float* __restrict__ f0, const float* __restrict__ f1,
    unsigned short* __restrict__ f0t, unsigned short* __restrict__ f1t) {
  __shared__ float tile[64][69];
  int bx = blockIdx.x;
  const float* src; unsigned short* dst; int HW, bv, ptile;
  if (bx < T0_TILES_) {
    src = f0; dst = f0t; HW = HW0_;
    bv = bx / (HW0_ / 64); ptile = bx % (HW0_ / 64);
  } else {
    bx -= T0_TILES_;
    src = f1; dst = f1t; HW = HW1_;
    bv = bx / (HW1_ / 64); ptile = bx % (HW1_ / 64);
  }
  const int p0 = ptile * 64;
  const int ct0 = blockIdx.y * 64;
  const size_t sbase = (size_t)bv * C_ * HW;
  const size_t dbase = (size_t)bv * HW * C_;
  const int tid = threadIdx.x;

  {  // read-in: coalesced f32x4 along HW
    const int px4 = (tid & 15) * 4;
    const int crow = tid >> 4;      // 0..15
    for (int j = 0; j < 64; j += 16) {
      const f4 v = __builtin_nontemporal_load(
          reinterpret_cast<const f4*>(
              src + sbase + (size_t)(ct0 + crow + j) * HW + p0 + px4));
      tile[crow + j][px4 + 0] = v.x;
      tile[crow + j][px4 + 1] = v.y;
      tile[crow + j][px4 + 2] = v.z;
      tile[crow + j][px4 + 3] = v.w;
    }
  }
  __syncthreads();
  {  // write-out: us8 (16B) coalesced along C
    const int cx8 = (tid & 7) * 8;
    const int prow = tid >> 3;      // 0..31
    for (int j = 0; j < 64; j += 32) {
      us8 o;
      #pragma unroll
      for (int k = 0; k < 8; ++k) o[k] = f2bf(tile[cx8 + k][prow + j]);
      *reinterpret_cast<us8*>(
          dst + dbase + (size_t)(p0 + prow + j) * C_ + ct0 + cx8) = o;
    }
  }
}

// ---------------------------------------------------------------------------
// Sampler (R6 structure + zero-weight load REDIRECTION): every L0 row load
// issues branch-free (deep pipelining preserved), but rows whose weight is
// exactly 0 get their pixel index cndmask'd to 0 -> all such loads across
// the grid hit the same hot 512B line (L1/L2 resident) -> ~no fabric bytes.
// ---------------------------------------------------------------------------
__global__ __launch_bounds__(256) void sampler_bf16(
    const unsigned short* __restrict__ f0t,   // [B,V,HW0,C] bf16
    const unsigned short* __restrict__ f1t,   // [B,V,HW1,C] bf16
    const float* __restrict__ xy,             // [NQ,24,2]
    const unsigned int* __restrict__ masks, const float* __restrict__ invs,
    float* __restrict__ out) {
  const int tid = threadIdx.x;
  const int wave = __builtin_amdgcn_readfirstlane(tid >> 6);
  const int lane = tid & 63;
  const int half = lane >> 5;
  const int cidx = lane & 31;      // 8 channels: 8*cidx .. 8*cidx+7
  const int idx = blockIdx.x * 4 + wave;   // b*Q + q  (SGPR)
  const int b = idx >> 11;

  const unsigned int mask = masks[idx];
  const float inv = invs[idx];
  const float* pxy = xy + (size_t)idx * 48;
  const int ce = cidx * 8;

  const unsigned short* F0 = f0t + (size_t)b * V_ * HW0_ * C_ + ce;
  const unsigned short* F1 = f1t + (size_t)b * V_ * HW1_ * C_ + ce;

  float acc[8] = {0.f, 0.f, 0.f, 0.f, 0.f, 0.f, 0.f, 0.f};

  #pragma unroll
  for (int s = 0; s < 24; ++s) {
    const bool valid = (mask >> s) & 1u;
    float x = pxy[2 * s], y = pxy[2 * s + 1];
    if (!valid) { x = 0.f; y = 0.f; }          // sanitize possible NaN/inf
    const float fvalid = valid ? 1.f : 0.f;
    const float x0f = floorf(x), y0f = floorf(y);
    const float wx1 = x - x0f, wy1 = y - y0f;
    const float wx0 = 1.f - wx1, wy0 = 1.f - wy1;
    const int v = s >> 2;

    // ---- level 0: branch-free with zero-weight redirection ----
    {
      const float Wm1 = (float)(W0_ - 1), Hm1 = (float)(H0_ - 1);
      const float xhf = half ? (x0f + 1.f) : x0f;
      const float bx = (xhf >= 0.f && xhf <= Wm1) ? 1.f : 0.f;
      const float by0 = (y0f >= 0.f && y0f <= Hm1) ? 1.f : 0.f;
      const float by1 = (y0f + 1.f >= 0.f && y0f + 1.f <= Hm1) ? 1.f : 0.f;
      const float wxh = (half ? wx1 : wx0) * bx * fvalid;
      const int xh  = (int)fminf(fmaxf(xhf, 0.f), Wm1);
      const int yi0 = (int)fminf(fmaxf(y0f, 0.f), Hm1);
      const int yi1 = (int)fminf(fmaxf(y0f + 1.f, 0.f), Hm1);
      const float w0 = wxh * wy0 * by0;
      const float w1 = wxh * wy1 * by1;
      // zero-weight rows -> pixel 0 (hot line, no fabric traffic)
      const int pix0 = (w0 != 0.f) ? (yi0 * W0_ + xh) : 0;
      const int pix1 = (w1 != 0.f) ? (yi1 * W0_ + xh) : 0;
      const unsigned short* Fv = F0 + (size_t)v * HW0_ * C_;
      const us8 u0 = *reinterpret_cast<const us8*>(Fv + (size_t)pix0 * C_);
      const us8 u1 = *reinterpret_cast<const us8*>(Fv + (size_t)pix1 * C_);
      #pragma unroll
      for (int k = 0; k < 8; ++k) {
        acc[k] = fmaf(w0, bf2f(u0[k]), acc[k]);
        acc[k] = fmaf(w1, bf2f(u1[k]), acc[k]);
      }
    }

    // ---- level 1: uniform skip (mostly OOB) + redirection inside ----
    {
      const float Wm1 = (float)(W1_ - 1), Hm1 = (float)(H1_ - 1);
      const float x1f = x0f + 1.f, y1f = y0f + 1.f;
      const bool bx0 = (x0f >= 0.f) && (x0f <= Wm1);
      const bool bx1 = (x1f >= 0.f) && (x1f <= Wm1);
      const bool by0 = (y0f >= 0.f) && (y0f <= Hm1);
      const bool by1 = (y1f >= 0.f) && (y1f <= Hm1);
      if (((bx0 || bx1) && (by0 || by1)) && valid) {
        const int xi0 = (int)fminf(fmaxf(x0f, 0.f), Wm1);
        const int xi1 = (int)fminf(fmaxf(x1f, 0.f), Wm1);
        const int xh = half ? xi1 : xi0;
        const float wxh = half ? (bx1 ? wx1 : 0.f) : (bx0 ? wx0 : 0.f);
        const int yi0 = (int)fminf(fmaxf(y0f, 0.f), Hm1);
        const int yi1 = (int)fminf(fmaxf(y1f, 0.f), Hm1);
        const float w0 = wxh * wy0 * (by0 ? 1.f : 0.f);
        const float w1 = wxh * wy1 * (by1 ? 1.f : 0.f);
        const int pix0 = (w0 != 0.f) ? (yi0 * W1_ + xh) : 0;
        const int pix1 = (w1 != 0.f) ? (yi1 * W1_ + xh) : 0;
        const unsigned short* Fv = F1 + (size_t)v * HW1_ * C_;
        const us8 u0 = *reinterpret_cast<const us8*>(Fv + (size_t)pix0 * C_);
        const us8 u1 = *reinterpret_cast<const us8*>(Fv + (size_t)pix1 * C_);
        #pragma unroll
        for (int k = 0; k < 8; ++k) {
          acc[k] = fmaf(w0, bf2f(u0[k]), acc[k]);
          acc[k] = fmaf(w1, bf2f(u1[k]), acc[k]);
        }
      }
    }
  }

  // cross-half reduce: lane i and i+32 hold the same 8 channels
  #pragma unroll
  for (int k = 0; k < 8; ++k) acc[k] += __shfl_xor(acc[k], 32);

  // store: half 0 writes ch [8c,8c+4), half 1 writes [8c+4,8c+8)
  f4 o;
  const int ko = half * 4;
  o.x = acc[ko + 0] * inv;
  o.y = acc[ko + 1] * inv;
  o.z = acc[ko + 2] * inv;
  o.w = acc[ko + 3] * inv;
  __builtin_nontemporal_store(
      o, reinterpret_cast<f4*>(out + (size_t)idx * C_ + ce + ko));
}

// ---------------------------------------------------------------------------
// Fallback: direct gather from [B,V,C,H,W] (used only if workspace too small)
// ---------------------------------------------------------------------------
__device__ __forceinline__ float bilinear_scalar(
    const float* __restrict__ fm, const int W, const int H,
    const float x, const float y) {
  const float x0f = floorf(x), y0f = floorf(y);
  const float wx1 = x - x0f, wy1 = y - y0f;
  const float wx0 = 1.f - wx1, wy0 = 1.f - wy1;
  const float x1f = x0f + 1.f, y1f = y0f + 1.f;
  const float Wm1 = (float)(W - 1), Hm1 = (float)(H - 1);
  const bool bx0 = (x0f >= 0.f) && (x0f <= Wm1);
  const bool bx1 = (x1f >= 0.f) && (x1f <= Wm1);
  const bool by0 = (y0f >= 0.f) && (y0f <= Hm1);
  const bool by1 = (y1f >= 0.f) && (y1f <= Hm1);
  if (!((bx0 || bx1) && (by0 || by1))) return 0.f;
  const int xi0 = (int)fminf(fmaxf(x0f, 0.f), Wm1);
  const int xi1 = (int)fminf(fmaxf(x1f, 0.f), Wm1);
  const int yi0 = (int)fminf(fmaxf(y0f, 0.f), Hm1);
  const int yi1 = (int)fminf(fmaxf(y1f, 0.f), Hm1);
  float r = 0.f;
  if (bx0 && by0) r = fmaf(wx0 * wy0, fm[yi0 * W + xi0], r);
  if (bx1 && by0) r = fmaf(wx1 * wy0, fm[yi0 * W + xi1], r);
  if (bx0 && by1) r = fmaf(wx0 * wy1, fm[yi1 * W + xi0], r);
  if (bx1 && by1) r = fmaf(wx1 * wy1, fm[yi1 * W + xi1], r);
  return r;
}

__global__ __launch_bounds__(256) void sampler_direct(
    const float* __restrict__ f0, const float* __restrict__ f1,
    const float* __restrict__ refs, const float* __restrict__ intr,
    const float* __restrict__ extr, float* __restrict__ out) {
  __shared__ float sx[24], sy[24], scnt;
  __shared__ unsigned int smask;
  const int tid = threadIdx.x;
  const int b = blockIdx.y, q = blockIdx.x;
  bool zvalid = false;
  if (tid < 24) {
    const int v = tid >> 2, kp = tid & 3;
    const float kx = (kp == 1) ? RADIUS_ : ((kp == 3) ? -RADIUS_ : 0.f);
    const float ky = (kp == 2) ? RADIUS_ : 0.f;
    const float rx = refs[((size_t)b * Q_ + q) * 3 + 0];
    const float ry = refs[((size_t)b * Q_ + q) * 3 + 1];
    const float rz = refs[((size_t)b * Q_ + q) * 3 + 2];
    const float px = rx + kx, py = ry + ky, pz = rz;
    const float* E = extr + ((size_t)b * V_ + v) * 16;
    const float cx = E[0] * px + E[1] * py + E[2]  * pz + E[3];
    const float cy = E[4] * px + E[5] * py + E[6]  * pz + E[7];
    const float cz = E[8] * px + E[9] * py + E[10] * pz + E[11];
    const float* K = intr + ((size_t)b * V_ + v) * 9;
    const float uu = K[0] * cx + K[1] * cy + K[2] * cz;
    const float vv = K[3] * cx + K[4] * cy + K[5] * cz;
    const float ww = K[6] * cx + K[7] * cy + K[8] * cz;
    const float zc = fmaxf(ww, 1e-5f);
    sx[tid] = uu / zc;
    sy[tid] = vv / zc;
    zvalid = (ww > 0.f);
  }
  const unsigned long long m = __ballot(zvalid);
  if (tid == 0) {
    const unsigned int mm = (unsigned int)(m & 0xFFFFFFULL);
    smask = mm;
    scnt = fmaxf((float)__popc(mm), 1.0f);
  }
  __syncthreads();
  const unsigned int mask = smask;
  const float cnt = scnt;
  const int c = tid;
  float a0 = 0.f, a1 = 0.f;
  for (int s = 0; s < 24; ++s) {
    if (!((mask >> s) & 1u)) continue;
    const float x = sx[s], y = sy[s];
    const int v = s >> 2;
    const size_t bv = (size_t)b * V_ + v;
    a0 += bilinear_scalar(f0 + (bv * C_ + c) * (size_t)HW0_, W0_, H0_, x, y);
    a1 += bilinear_scalar(f1 + (bv * C_ + c) * (size_t)HW1_, W1_, H1_, x, y);
  }
  out[((size_t)b * Q_ + q) * C_ + c] = (a0 + a1) * 0.5f / cnt;
}

// ---------------------------------------------------------------------------
extern "C" void kernel_launch(void* const* d_in, const int* in_sizes, int n_in,
                              void* d_out, int out_size, void* d_ws, size_t ws_size,
                              hipStream_t stream) {
  const float* feat0 = (const float*)d_in[0];
  const float* feat1 = (const float*)d_in[1];
  const float* refs  = (const float*)d_in[2];
  const float* intr  = (const float*)d_in[3];
  const float* extr  = (const float*)d_in[4];
  float* out = (float*)d_out;

  const size_t need = F0_ELEMS * 2 + F1_ELEMS * 2          // bf16 copies
                    + ((size_t)NQ_ * 48 + 2 * NQ_) * 4;    // xy + mask + inv

  if (ws_size >= need) {
    unsigned short* f0t = (unsigned short*)d_ws;
    unsigned short* f1t = f0t + F0_ELEMS;
    float* xy = (float*)(f1t + F1_ELEMS);
    unsigned int* masks = (unsigned int*)(xy + (size_t)NQ_ * 48);
    float* invs = (float*)(masks + NQ_);

    proj_kernel<<<NQ_ / 256, 256, 0, stream>>>(refs, intr, extr, xy, masks, invs);
    transpose_bf16<<<dim3(T0_TILES_ + T1_TILES_, C_ / 64), 256, 0, stream>>>(
        feat0, feat1, f0t, f1t);
    sampler_bf16<<<dim3(NQ_ / 4), 256, 0, stream>>>(
        f0t, f1t, xy, masks, invs, out);
  } else {
    sampler_direct<<<dim3(Q_, B_), 256, 0, stream>>>(
        feat0, feat1, refs, intr, extr, out);
  }
}